// Round 7
// baseline (468.136 us; speedup 1.0000x reference)
//
#include <hip/hip_runtime.h>

typedef __attribute__((ext_vector_type(8))) short short8;
typedef __attribute__((ext_vector_type(4))) float f32x4;
typedef unsigned short u16;
typedef unsigned int u32;

__device__ __forceinline__ float bf2f(u16 u) {
    union { u32 i; float f; } x;
    x.i = ((u32)u) << 16;
    return x.f;
}

__device__ __forceinline__ u16 f2bf(float f) {
    union { float f; u32 i; } x;
    x.f = f;
    u32 r = x.i + 0x7fffu + ((x.i >> 16) & 1u);  // RNE
    return (u16)(r >> 16);
}

// ---------------------------------------------------------------------------
// fp32 -> bf16 elementwise (n divisible by 2048)
// ---------------------------------------------------------------------------
__global__ __launch_bounds__(256) void convert_bf16(const float* __restrict__ in,
                                                    u16* __restrict__ out) {
    const long i = ((long)blockIdx.x * 256 + threadIdx.x) * 8;
    f32x4 v0 = *(const f32x4*)(in + i);
    f32x4 v1 = *(const f32x4*)(in + i + 4);
    short8 o;
#pragma unroll
    for (int j = 0; j < 4; ++j) o[j] = (short)f2bf(v0[j]);
#pragma unroll
    for (int j = 0; j < 4; ++j) o[4 + j] = (short)f2bf(v1[j]);
    *(short8*)(out + i) = o;
}

// ---------------------------------------------------------------------------
// fp32 [K][N] -> bf16 [N][K] transpose+convert
// ---------------------------------------------------------------------------
__global__ __launch_bounds__(256) void transpose_f32_bf16(const float* __restrict__ in,
                                                          u16* __restrict__ out,
                                                          int K, int N) {
    __shared__ float tile[32][33];
    const int nb = blockIdx.x * 32, kb = blockIdx.y * 32;
    const int tx = threadIdx.x, ty = threadIdx.y;  // 32 x 8
#pragma unroll
    for (int i = 0; i < 32; i += 8)
        tile[ty + i][tx] = in[(long)(kb + ty + i) * N + nb + tx];
    __syncthreads();
#pragma unroll
    for (int i = 0; i < 32; i += 8)
        out[(long)(nb + ty + i) * K + kb + tx] = f2bf(tile[tx][ty + i]);
}

// ---------------------------------------------------------------------------
// V transpose: qkv V slots [b*2048+t][2048 + h*64 + d] -> vT[bh][d][t]
// ---------------------------------------------------------------------------
__global__ __launch_bounds__(256) void transpose_v(const u16* __restrict__ qkv,
                                                   u16* __restrict__ vT) {
    __shared__ u16 tile[32][33];
    const int tb = blockIdx.x * 32;  // t
    const int db = blockIdx.y * 32;  // d
    const int bh = blockIdx.z;
    const int b = bh >> 4, h = bh & 15;
    const int tx = threadIdx.x, ty = threadIdx.y;  // 32 x 8
#pragma unroll
    for (int i = 0; i < 32; i += 8)
        tile[ty + i][tx] = qkv[((long)b * 2048 + tb + ty + i) * 3072 + 2048 + h * 64 + db + tx];
    __syncthreads();
#pragma unroll
    for (int i = 0; i < 32; i += 8)
        vT[((long)bh * 64 + db + ty + i) * 2048 + tb + tx] = tile[tx][ty + i];
}

// ---------------------------------------------------------------------------
// GEMM1: C[M,N](bf16) = A[M,K](bf16, lda) @ BT[N,K](bf16)^T + bias(f32)
// ---------------------------------------------------------------------------
__global__ __launch_bounds__(256, 2) void gemm_bf16_bt(
    const u16* __restrict__ A, int lda, const u16* __restrict__ BT,
    const float* __restrict__ bias, u16* __restrict__ C,
    int M, int N, int K) {
    __shared__ u16 As[128 * 32];
    __shared__ u16 Bs[128 * 32];
    const int tid = threadIdx.x;
    const int wv = tid >> 6, lane = tid & 63, quad = lane >> 4, L = lane & 15;
    const int wm = (wv >> 1) * 64, wn = (wv & 1) * 64;
    const long m0 = (long)blockIdx.y * 128;
    const long n0 = (long)blockIdx.x * 128;

    const u16* Ag = A + (m0 + wv * 32 + (lane >> 2)) * (long)lda + (lane & 3) * 8;
    const u16* Bg = BT + (n0 + wv * 32 + (lane >> 2)) * (long)K + (lane & 3) * 8;
    u16* AsW = &As[wv * 32 * 32];
    u16* BsW = &Bs[wv * 32 * 32];

    f32x4 zero4 = {0.f, 0.f, 0.f, 0.f};
    f32x4 acc[4][4];
#pragma unroll
    for (int i = 0; i < 4; ++i)
#pragma unroll
        for (int j = 0; j < 4; ++j) acc[i][j] = zero4;

    for (int kb = 0; kb < K; kb += 32) {
        short8 a0 = *(const short8*)(Ag + kb);
        short8 a1 = *(const short8*)(Ag + kb + (long)16 * lda);
        short8 b0 = *(const short8*)(Bg + kb);
        short8 b1 = *(const short8*)(Bg + kb + (long)16 * K);
        __syncthreads();
        *(short8*)(AsW + lane * 8) = a0;
        *(short8*)(AsW + 512 + lane * 8) = a1;
        *(short8*)(BsW + lane * 8) = b0;
        *(short8*)(BsW + 512 + lane * 8) = b1;
        __syncthreads();

        short8 af[4], bf[4];
#pragma unroll
        for (int mt = 0; mt < 4; ++mt)
            af[mt] = *(const short8*)&As[(wm + mt * 16 + L) * 32 + quad * 8];
#pragma unroll
        for (int nt = 0; nt < 4; ++nt)
            bf[nt] = *(const short8*)&Bs[(wn + nt * 16 + L) * 32 + quad * 8];
#pragma unroll
        for (int mt = 0; mt < 4; ++mt)
#pragma unroll
            for (int nt = 0; nt < 4; ++nt)
                acc[mt][nt] = __builtin_amdgcn_mfma_f32_16x16x32_bf16(
                    af[mt], bf[nt], acc[mt][nt], 0, 0, 0);
    }

#pragma unroll
    for (int nt = 0; nt < 4; ++nt) {
        const long col = n0 + wn + nt * 16 + L;
        const float bv = bias[col];
#pragma unroll
        for (int mt = 0; mt < 4; ++mt)
#pragma unroll
            for (int r = 0; r < 4; ++r) {
                const long row = m0 + wm + mt * 16 + quad * 4 + r;
                C[row * N + col] = f2bf(acc[mt][nt][r] + bv);
            }
    }
}

// ---------------------------------------------------------------------------
// GEMM2: C[M,N](f32) = A[M,K](bf16, lda) @ B[K,N](f32) + bias(f32)
// ---------------------------------------------------------------------------
__global__ __launch_bounds__(256, 2) void gemm_bf16_bn(
    const u16* __restrict__ A, int lda, const float* __restrict__ B,
    const float* __restrict__ bias, float* __restrict__ C,
    int M, int N, int K) {
    __shared__ u16 As[128 * 32];
    __shared__ u16 Bs[128 * 32];
    const int tid = threadIdx.x;
    const int wv = tid >> 6, lane = tid & 63, quad = lane >> 4, L = lane & 15;
    const int wm = (wv >> 1) * 64, wn = (wv & 1) * 64;
    const long m0 = (long)blockIdx.y * 128;
    const long n0 = (long)blockIdx.x * 128;

    const u16* Ag = A + (m0 + wv * 32 + (lane >> 2)) * (long)lda + (lane & 3) * 8;
    u16* AsW = &As[wv * 32 * 32];

    f32x4 zero4 = {0.f, 0.f, 0.f, 0.f};
    f32x4 acc[4][4];
#pragma unroll
    for (int i = 0; i < 4; ++i)
#pragma unroll
        for (int j = 0; j < 4; ++j) acc[i][j] = zero4;

    for (int kb = 0; kb < K; kb += 32) {
        short8 a0 = *(const short8*)(Ag + kb);
        short8 a1 = *(const short8*)(Ag + kb + (long)16 * lda);
        short8 p[2];
#pragma unroll
        for (int i = 0; i < 2; ++i) {
            const int c = tid + i * 256;
            const int n = c >> 2, k8 = (c & 3) * 8;
            const float* bp = B + (long)(kb + k8) * N + n0 + n;
#pragma unroll
            for (int j = 0; j < 8; ++j) p[i][j] = (short)f2bf(bp[(long)j * N]);
        }
        __syncthreads();
        *(short8*)(AsW + lane * 8) = a0;
        *(short8*)(AsW + 512 + lane * 8) = a1;
        *(short8*)(&Bs[tid * 8]) = p[0];
        *(short8*)(&Bs[(tid + 256) * 8]) = p[1];
        __syncthreads();

        short8 af[4], bf[4];
#pragma unroll
        for (int mt = 0; mt < 4; ++mt)
            af[mt] = *(const short8*)&As[(wm + mt * 16 + L) * 32 + quad * 8];
#pragma unroll
        for (int nt = 0; nt < 4; ++nt)
            bf[nt] = *(const short8*)&Bs[(wn + nt * 16 + L) * 32 + quad * 8];
#pragma unroll
        for (int mt = 0; mt < 4; ++mt)
#pragma unroll
            for (int nt = 0; nt < 4; ++nt)
                acc[mt][nt] = __builtin_amdgcn_mfma_f32_16x16x32_bf16(
                    af[mt], bf[nt], acc[mt][nt], 0, 0, 0);
    }

#pragma unroll
    for (int nt = 0; nt < 4; ++nt) {
        const long col = n0 + wn + nt * 16 + L;
        const float bv = bias[col];
#pragma unroll
        for (int mt = 0; mt < 4; ++mt)
#pragma unroll
            for (int r = 0; r < 4; ++r) {
                const long row = m0 + wm + mt * 16 + quad * 4 + r;
                C[row * N + col] = acc[mt][nt][r] + bv;
            }
    }
}

// ---------------------------------------------------------------------------
// Flash attention (causal), bf16, barrier-free. Fixed-max softmax (m=20).
// K fragments loaded directly from qkv rows (16B/lane contiguous); V fragments
// from pre-transposed vT[bh][d][t] (16B/lane contiguous). Only LDS use: the
// per-wave Ps round-trip (within-wave, no barrier — validated R6). Output
// written into the Q slots of qkv. Grid (bh fast=64, qt=32): all qtile blocks
// of one bh land on one XCD (64%8==0) so K/V stay L2-resident.
// ---------------------------------------------------------------------------
#define AT_T 2048

__global__ __launch_bounds__(256, 4) void attn_kernel(u16* __restrict__ qkv,
                                                      const u16* __restrict__ vT) {
    __shared__ u16 Ps[4][16 * 72];
    const int tid = threadIdx.x;
    const int wv = tid >> 6, lane = tid & 63, quad = lane >> 4, L = lane & 15;
    const int bh = blockIdx.x;
    const int qtile = 31 - (int)blockIdx.y;  // heavy first
    const int b = bh >> 4, h = bh & 15;
    const long rowbase = (long)b * AT_T;
    const long cbase = (long)h * 64;

    // Q fragments (A layout: m=L, k=quad*8+j)
    const int qm = qtile * 64 + wv * 16 + L;
    short8 qf[2];
#pragma unroll
    for (int s = 0; s < 2; ++s)
        qf[s] = *(const short8*)&qkv[(rowbase + qm) * 3072 + cbase + s * 32 + quad * 8];

    // ones B-fragment: column 0 accumulates row sums
    short8 ones;
#pragma unroll
    for (int j = 0; j < 8; ++j) ones[j] = (L == 0) ? (short)0x3F80 : (short)0;

    // K fragment base: row (k0+nt*16+L), bytes s*32+quad*8 within head
    const u16* Kb = qkv + (rowbase + L) * 3072 + 1024 + cbase + quad * 8;
    // V fragment base: vT row (bh*64 + nt*16+L), t offset k0+s*32+quad*8
    const u16* Vb = vT + ((long)bh * 64 + L) * 2048 + quad * 8;

    f32x4 zero4 = {0.f, 0.f, 0.f, 0.f};
    f32x4 accO[4], accL = zero4;
#pragma unroll
    for (int nt = 0; nt < 4; ++nt) accO[nt] = zero4;
    int qg[4];
#pragma unroll
    for (int r = 0; r < 4; ++r) qg[r] = qtile * 64 + wv * 16 + quad * 4 + r;

    const int nkb = qtile + 1;
    for (int kb = 0; kb < nkb; ++kb) {
        const int k0 = kb * 64;

        // K fragments (8 x 16B loads) + QK^T
        f32x4 sA[4];
#pragma unroll
        for (int nt = 0; nt < 4; ++nt) {
            const u16* kp = Kb + (long)(k0 + nt * 16) * 3072;
            short8 kf0 = *(const short8*)(kp);
            short8 kf1 = *(const short8*)(kp + 32);
            f32x4 z = zero4;
            z = __builtin_amdgcn_mfma_f32_16x16x32_bf16(qf[0], kf0, z, 0, 0, 0);
            z = __builtin_amdgcn_mfma_f32_16x16x32_bf16(qf[1], kf1, z, 0, 0, 0);
            sA[nt] = z;
        }

        // V fragments issued early (overlap with exp)
        short8 vfr[2][4];
#pragma unroll
        for (int s = 0; s < 2; ++s)
#pragma unroll
            for (int nt = 0; nt < 4; ++nt)
                vfr[s][nt] = *(const short8*)(Vb + (long)(nt * 16) * 2048 + k0 + s * 32);

        // p = exp(s*0.125 - 20), trunc-pack to bf16 (bias cancels in O/l)
        if (kb == qtile) {  // diagonal: causal mask
#pragma unroll
            for (int nt = 0; nt < 4; ++nt) {
                const int key = k0 + nt * 16 + L;
#pragma unroll
                for (int r = 0; r < 4; ++r) {
                    const float v = (key <= qg[r]) ? fmaf(sA[nt][r], 0.125f, -20.0f) : -1e30f;
                    Ps[wv][(quad * 4 + r) * 72 + nt * 16 + L] =
                        (u16)(__float_as_uint(__expf(v)) >> 16);
                }
            }
        } else {
#pragma unroll
            for (int nt = 0; nt < 4; ++nt)
#pragma unroll
                for (int r = 0; r < 4; ++r) {
                    const float p = __expf(fmaf(sA[nt][r], 0.125f, -20.0f));
                    Ps[wv][(quad * 4 + r) * 72 + nt * 16 + L] =
                        (u16)(__float_as_uint(p) >> 16);
                }
        }

        // PV + row-sum; P via per-wave LDS (C->A layout transform)
#pragma unroll
        for (int s = 0; s < 2; ++s) {
            short8 pf = *(const short8*)&Ps[wv][L * 72 + s * 32 + quad * 8];
            accL = __builtin_amdgcn_mfma_f32_16x16x32_bf16(pf, ones, accL, 0, 0, 0);
#pragma unroll
            for (int nt = 0; nt < 4; ++nt)
                accO[nt] = __builtin_amdgcn_mfma_f32_16x16x32_bf16(pf, vfr[s][nt], accO[nt], 0, 0, 0);
        }
    }

    // l is in column 0 (lane quad*16), reg r; broadcast + normalize
#pragma unroll
    for (int r = 0; r < 4; ++r) {
        const float l = __shfl(accL[r], lane & 48);
        const float inv = 1.f / l;
        const long orow = (rowbase + qg[r]) * 3072 + cbase;
#pragma unroll
        for (int nt = 0; nt < 4; ++nt)
            qkv[orow + nt * 16 + L] = f2bf(accO[nt][r] * inv);
    }
}

// ---------------------------------------------------------------------------
extern "C" void kernel_launch(void* const* d_in, const int* in_sizes, int n_in,
                              void* d_out, int out_size, void* d_ws, size_t ws_size,
                              hipStream_t stream) {
    const float* x      = (const float*)d_in[0];
    const float* w_attn = (const float*)d_in[1];
    const float* b_attn = (const float*)d_in[2];
    const float* w_proj = (const float*)d_in[3];
    const float* b_proj = (const float*)d_in[4];
    float* out = (float*)d_out;

    u16* qkv = (u16*)d_ws;                      // [8192,3072] bf16 (50.33 MB)
    u16* xb  = (u16*)d_out;                     // [8192,1024] bf16 scratch (dies at GEMM1)
    u16* wTa = (u16*)((char*)d_out + 16777216); // [3072,1024] bf16 scratch (dies at GEMM1)
    u16* vT  = (u16*)d_out;                     // [64,64,2048] bf16 scratch (dies at GEMM2)

    convert_bf16<<<4096, 256, 0, stream>>>(x, xb);
    transpose_f32_bf16<<<dim3(3072 / 32, 1024 / 32), dim3(32, 8), 0, stream>>>(
        w_attn, wTa, 1024, 3072);
    gemm_bf16_bt<<<dim3(3072 / 128, 8192 / 128), 256, 0, stream>>>(
        xb, 1024, wTa, b_attn, qkv, 8192, 3072, 1024);
    transpose_v<<<dim3(64, 2, 64), dim3(32, 8), 0, stream>>>(qkv, vT);
    attn_kernel<<<dim3(64, 32), 256, 0, stream>>>(qkv, vT);
    gemm_bf16_bn<<<dim3(1024 / 128, 8192 / 128), 256, 0, stream>>>(
        qkv, 3072, w_proj, b_proj, out, 8192, 1024, 1024);
}

// Round 8
// 467.316 us; speedup vs baseline: 1.0018x; 1.0018x over previous
//
#include <hip/hip_runtime.h>

typedef __attribute__((ext_vector_type(8))) short short8;
typedef __attribute__((ext_vector_type(4))) float f32x4;
typedef unsigned short u16;
typedef unsigned int u32;

__device__ __forceinline__ float bf2f(u16 u) {
    union { u32 i; float f; } x;
    x.i = ((u32)u) << 16;
    return x.f;
}

__device__ __forceinline__ u16 f2bf(float f) {
    union { float f; u32 i; } x;
    x.f = f;
    u32 r = x.i + 0x7fffu + ((x.i >> 16) & 1u);  // RNE
    return (u16)(r >> 16);
}

// ---------------------------------------------------------------------------
// fp32 -> bf16 elementwise (n divisible by 2048)
// ---------------------------------------------------------------------------
__global__ __launch_bounds__(256) void convert_bf16(const float* __restrict__ in,
                                                    u16* __restrict__ out) {
    const long i = ((long)blockIdx.x * 256 + threadIdx.x) * 8;
    f32x4 v0 = *(const f32x4*)(in + i);
    f32x4 v1 = *(const f32x4*)(in + i + 4);
    short8 o;
#pragma unroll
    for (int j = 0; j < 4; ++j) o[j] = (short)f2bf(v0[j]);
#pragma unroll
    for (int j = 0; j < 4; ++j) o[4 + j] = (short)f2bf(v1[j]);
    *(short8*)(out + i) = o;
}

// ---------------------------------------------------------------------------
// fp32 [K][N] -> bf16 [N][K] transpose+convert
// ---------------------------------------------------------------------------
__global__ __launch_bounds__(256) void transpose_f32_bf16(const float* __restrict__ in,
                                                          u16* __restrict__ out,
                                                          int K, int N) {
    __shared__ float tile[32][33];
    const int nb = blockIdx.x * 32, kb = blockIdx.y * 32;
    const int tx = threadIdx.x, ty = threadIdx.y;  // 32 x 8
#pragma unroll
    for (int i = 0; i < 32; i += 8)
        tile[ty + i][tx] = in[(long)(kb + ty + i) * N + nb + tx];
    __syncthreads();
#pragma unroll
    for (int i = 0; i < 32; i += 8)
        out[(long)(nb + ty + i) * K + kb + tx] = f2bf(tile[tx][ty + i]);
}

// ---------------------------------------------------------------------------
// V transpose: qkv V slots [b*2048+t][2048 + h*64 + d] -> vT[bh][d][t]
// ---------------------------------------------------------------------------
__global__ __launch_bounds__(256) void transpose_v(const u16* __restrict__ qkv,
                                                   u16* __restrict__ vT) {
    __shared__ u16 tile[32][33];
    const int tb = blockIdx.x * 32;  // t
    const int db = blockIdx.y * 32;  // d
    const int bh = blockIdx.z;
    const int b = bh >> 4, h = bh & 15;
    const int tx = threadIdx.x, ty = threadIdx.y;  // 32 x 8
#pragma unroll
    for (int i = 0; i < 32; i += 8)
        tile[ty + i][tx] = qkv[((long)b * 2048 + tb + ty + i) * 3072 + 2048 + h * 64 + db + tx];
    __syncthreads();
#pragma unroll
    for (int i = 0; i < 32; i += 8)
        vT[((long)bh * 64 + db + ty + i) * 2048 + tb + tx] = tile[tx][ty + i];
}

// ---------------------------------------------------------------------------
// GEMM1: C[M,N](bf16) = A[M,K](bf16, lda) @ BT[N,K](bf16)^T + bias(f32)
// ---------------------------------------------------------------------------
__global__ __launch_bounds__(256, 2) void gemm_bf16_bt(
    const u16* __restrict__ A, int lda, const u16* __restrict__ BT,
    const float* __restrict__ bias, u16* __restrict__ C,
    int M, int N, int K) {
    __shared__ u16 As[128 * 32];
    __shared__ u16 Bs[128 * 32];
    const int tid = threadIdx.x;
    const int wv = tid >> 6, lane = tid & 63, quad = lane >> 4, L = lane & 15;
    const int wm = (wv >> 1) * 64, wn = (wv & 1) * 64;
    const long m0 = (long)blockIdx.y * 128;
    const long n0 = (long)blockIdx.x * 128;

    const u16* Ag = A + (m0 + wv * 32 + (lane >> 2)) * (long)lda + (lane & 3) * 8;
    const u16* Bg = BT + (n0 + wv * 32 + (lane >> 2)) * (long)K + (lane & 3) * 8;
    u16* AsW = &As[wv * 32 * 32];
    u16* BsW = &Bs[wv * 32 * 32];

    f32x4 zero4 = {0.f, 0.f, 0.f, 0.f};
    f32x4 acc[4][4];
#pragma unroll
    for (int i = 0; i < 4; ++i)
#pragma unroll
        for (int j = 0; j < 4; ++j) acc[i][j] = zero4;

    for (int kb = 0; kb < K; kb += 32) {
        short8 a0 = *(const short8*)(Ag + kb);
        short8 a1 = *(const short8*)(Ag + kb + (long)16 * lda);
        short8 b0 = *(const short8*)(Bg + kb);
        short8 b1 = *(const short8*)(Bg + kb + (long)16 * K);
        __syncthreads();
        *(short8*)(AsW + lane * 8) = a0;
        *(short8*)(AsW + 512 + lane * 8) = a1;
        *(short8*)(BsW + lane * 8) = b0;
        *(short8*)(BsW + 512 + lane * 8) = b1;
        __syncthreads();

        short8 af[4], bf[4];
#pragma unroll
        for (int mt = 0; mt < 4; ++mt)
            af[mt] = *(const short8*)&As[(wm + mt * 16 + L) * 32 + quad * 8];
#pragma unroll
        for (int nt = 0; nt < 4; ++nt)
            bf[nt] = *(const short8*)&Bs[(wn + nt * 16 + L) * 32 + quad * 8];
#pragma unroll
        for (int mt = 0; mt < 4; ++mt)
#pragma unroll
            for (int nt = 0; nt < 4; ++nt)
                acc[mt][nt] = __builtin_amdgcn_mfma_f32_16x16x32_bf16(
                    af[mt], bf[nt], acc[mt][nt], 0, 0, 0);
    }

#pragma unroll
    for (int nt = 0; nt < 4; ++nt) {
        const long col = n0 + wn + nt * 16 + L;
        const float bv = bias[col];
#pragma unroll
        for (int mt = 0; mt < 4; ++mt)
#pragma unroll
            for (int r = 0; r < 4; ++r) {
                const long row = m0 + wm + mt * 16 + quad * 4 + r;
                C[row * N + col] = f2bf(acc[mt][nt][r] + bv);
            }
    }
}

// ---------------------------------------------------------------------------
// GEMM2: C[M,N](f32) = A[M,K](bf16, lda) @ B[K,N](f32) + bias(f32)
// ---------------------------------------------------------------------------
__global__ __launch_bounds__(256, 2) void gemm_bf16_bn(
    const u16* __restrict__ A, int lda, const float* __restrict__ B,
    const float* __restrict__ bias, float* __restrict__ C,
    int M, int N, int K) {
    __shared__ u16 As[128 * 32];
    __shared__ u16 Bs[128 * 32];
    const int tid = threadIdx.x;
    const int wv = tid >> 6, lane = tid & 63, quad = lane >> 4, L = lane & 15;
    const int wm = (wv >> 1) * 64, wn = (wv & 1) * 64;
    const long m0 = (long)blockIdx.y * 128;
    const long n0 = (long)blockIdx.x * 128;

    const u16* Ag = A + (m0 + wv * 32 + (lane >> 2)) * (long)lda + (lane & 3) * 8;
    u16* AsW = &As[wv * 32 * 32];

    f32x4 zero4 = {0.f, 0.f, 0.f, 0.f};
    f32x4 acc[4][4];
#pragma unroll
    for (int i = 0; i < 4; ++i)
#pragma unroll
        for (int j = 0; j < 4; ++j) acc[i][j] = zero4;

    for (int kb = 0; kb < K; kb += 32) {
        short8 a0 = *(const short8*)(Ag + kb);
        short8 a1 = *(const short8*)(Ag + kb + (long)16 * lda);
        short8 p[2];
#pragma unroll
        for (int i = 0; i < 2; ++i) {
            const int c = tid + i * 256;
            const int n = c >> 2, k8 = (c & 3) * 8;
            const float* bp = B + (long)(kb + k8) * N + n0 + n;
#pragma unroll
            for (int j = 0; j < 8; ++j) p[i][j] = (short)f2bf(bp[(long)j * N]);
        }
        __syncthreads();
        *(short8*)(AsW + lane * 8) = a0;
        *(short8*)(AsW + 512 + lane * 8) = a1;
        *(short8*)(&Bs[tid * 8]) = p[0];
        *(short8*)(&Bs[(tid + 256) * 8]) = p[1];
        __syncthreads();

        short8 af[4], bf[4];
#pragma unroll
        for (int mt = 0; mt < 4; ++mt)
            af[mt] = *(const short8*)&As[(wm + mt * 16 + L) * 32 + quad * 8];
#pragma unroll
        for (int nt = 0; nt < 4; ++nt)
            bf[nt] = *(const short8*)&Bs[(wn + nt * 16 + L) * 32 + quad * 8];
#pragma unroll
        for (int mt = 0; mt < 4; ++mt)
#pragma unroll
            for (int nt = 0; nt < 4; ++nt)
                acc[mt][nt] = __builtin_amdgcn_mfma_f32_16x16x32_bf16(
                    af[mt], bf[nt], acc[mt][nt], 0, 0, 0);
    }

#pragma unroll
    for (int nt = 0; nt < 4; ++nt) {
        const long col = n0 + wn + nt * 16 + L;
        const float bv = bias[col];
#pragma unroll
        for (int mt = 0; mt < 4; ++mt)
#pragma unroll
            for (int r = 0; r < 4; ++r) {
                const long row = m0 + wm + mt * 16 + quad * 4 + r;
                C[row * N + col] = acc[mt][nt][r] + bv;
            }
    }
}

// ---------------------------------------------------------------------------
// Flash attention (causal), bf16, fixed-max softmax (m=20 — key blocks are
// order-independent, so the 4 waves SPLIT THE KEY DIMENSION and combine via
// LDS float atomics). Each wave handles all 64 queries of the tile (4 m-frags)
// per key-block -> 72 MFMA per chain instance. Workgroup processes the qtile
// pair (31-by, by): constant 33 kb-units -> perfect load balance.
// K direct from qkv rows; V from pre-transposed vT[bh][d][t]. Output -> Q
// slots of qkv.
// ---------------------------------------------------------------------------
#define AT_T 2048

__global__ __launch_bounds__(256) void attn_kernel(u16* __restrict__ qkv,
                                                   const u16* __restrict__ vT) {
    __shared__ u16 Ps[4][64 * 72];   // per-wave P round-trip (36.9 KB)
    __shared__ float Os[64 * 73];    // combine buffer (+pad pitch 73)
    __shared__ float ls[64];
    const int tid = threadIdx.x;
    const int wv = tid >> 6, lane = tid & 63, quad = lane >> 4, L = lane & 15;
    const int bh = blockIdx.x;
    const int b = bh >> 4, h = bh & 15;
    const long rowbase = (long)b * AT_T;
    const long cbase = (long)h * 64;

    // ones B-fragment: column 0 accumulates row sums
    short8 ones;
#pragma unroll
    for (int j = 0; j < 8; ++j) ones[j] = (L == 0) ? (short)0x3F80 : (short)0;

    const u16* Kb = qkv + (rowbase + L) * 3072 + 1024 + cbase + quad * 8;
    const u16* Vb = vT + ((long)bh * 64 + L) * 2048 + quad * 8;
    u16* PsW = Ps[wv];

    f32x4 zero4 = {0.f, 0.f, 0.f, 0.f};

    for (int pass = 0; pass < 2; ++pass) {
        const int qtile = (pass == 0) ? (31 - (int)blockIdx.y) : (int)blockIdx.y;
        const int q0 = qtile * 64;

        // zero combine buffers
        for (int i = tid; i < 64 * 73; i += 256) Os[i] = 0.f;
        if (tid < 64) ls[tid] = 0.f;
        __syncthreads();

        // Q fragments: all 64 queries of the tile (A layout m=L, k=quad*8+j)
        short8 qf[4][2];
#pragma unroll
        for (int mq = 0; mq < 4; ++mq)
#pragma unroll
            for (int s = 0; s < 2; ++s)
                qf[mq][s] = *(const short8*)&qkv[(rowbase + q0 + mq * 16 + L) * 3072 +
                                                 cbase + s * 32 + quad * 8];

        f32x4 accO[4][4], accL[4];
#pragma unroll
        for (int mq = 0; mq < 4; ++mq) {
            accL[mq] = zero4;
#pragma unroll
            for (int nt = 0; nt < 4; ++nt) accO[mq][nt] = zero4;
        }

        const int nkb = qtile + 1;
        for (int kb = wv; kb < nkb; kb += 4) {
            const int k0 = kb * 64;

            // K fragments (B layout: n=key, k=d)
            short8 kf[2][4];
#pragma unroll
            for (int nt = 0; nt < 4; ++nt) {
                const u16* kp = Kb + (long)(k0 + nt * 16) * 3072;
                kf[0][nt] = *(const short8*)(kp);
                kf[1][nt] = *(const short8*)(kp + 32);
            }
            // V fragments (B layout: n=d, k=key) — issue early
            short8 vf[2][4];
#pragma unroll
            for (int s = 0; s < 2; ++s)
#pragma unroll
                for (int nt = 0; nt < 4; ++nt)
                    vf[s][nt] = *(const short8*)(Vb + (long)(nt * 16) * 2048 + k0 + s * 32);

            // per q-frag: QK^T -> exp -> Ps
#pragma unroll
            for (int mq = 0; mq < 4; ++mq) {
                f32x4 sA[4];
#pragma unroll
                for (int nt = 0; nt < 4; ++nt) {
                    f32x4 z = __builtin_amdgcn_mfma_f32_16x16x32_bf16(qf[mq][0], kf[0][nt], zero4, 0, 0, 0);
                    sA[nt] = __builtin_amdgcn_mfma_f32_16x16x32_bf16(qf[mq][1], kf[1][nt], z, 0, 0, 0);
                }
                if (kb == qtile) {  // diagonal: causal mask
#pragma unroll
                    for (int nt = 0; nt < 4; ++nt) {
                        const int key = k0 + nt * 16 + L;
#pragma unroll
                        for (int r = 0; r < 4; ++r) {
                            const int qq = q0 + mq * 16 + quad * 4 + r;
                            const float v = (key <= qq) ? fmaf(sA[nt][r], 0.125f, -20.0f) : -1e30f;
                            PsW[(mq * 16 + quad * 4 + r) * 72 + nt * 16 + L] =
                                (u16)(__float_as_uint(__expf(v)) >> 16);
                        }
                    }
                } else {
#pragma unroll
                    for (int nt = 0; nt < 4; ++nt)
#pragma unroll
                        for (int r = 0; r < 4; ++r) {
                            const float p = __expf(fmaf(sA[nt][r], 0.125f, -20.0f));
                            PsW[(mq * 16 + quad * 4 + r) * 72 + nt * 16 + L] =
                                (u16)(__float_as_uint(p) >> 16);
                        }
                }
            }

            // PV + row-sums (P via per-wave LDS C->A transform)
#pragma unroll
            for (int mq = 0; mq < 4; ++mq)
#pragma unroll
                for (int s = 0; s < 2; ++s) {
                    short8 pf = *(const short8*)&PsW[(mq * 16 + L) * 72 + s * 32 + quad * 8];
                    accL[mq] = __builtin_amdgcn_mfma_f32_16x16x32_bf16(pf, ones, accL[mq], 0, 0, 0);
#pragma unroll
                    for (int nt = 0; nt < 4; ++nt)
                        accO[mq][nt] = __builtin_amdgcn_mfma_f32_16x16x32_bf16(
                            pf, vf[s][nt], accO[mq][nt], 0, 0, 0);
                }
        }

        // combine partials across the 4 key-split waves (zero done pre-loop)
#pragma unroll
        for (int mq = 0; mq < 4; ++mq) {
#pragma unroll
            for (int nt = 0; nt < 4; ++nt)
#pragma unroll
                for (int r = 0; r < 4; ++r)
                    atomicAdd(&Os[(mq * 16 + quad * 4 + r) * 73 + nt * 16 + L],
                              accO[mq][nt][r]);
            if (L == 0) {
#pragma unroll
                for (int r = 0; r < 4; ++r)
                    atomicAdd(&ls[mq * 16 + quad * 4 + r], accL[mq][r]);
            }
        }
        __syncthreads();

        // normalize + store into Q slots
        {
            const int row = tid >> 2, cg = (tid & 3) * 16;
            const float inv = 1.f / ls[row];
            short8 o0, o1;
#pragma unroll
            for (int j = 0; j < 8; ++j) {
                o0[j] = (short)f2bf(Os[row * 73 + cg + j] * inv);
                o1[j] = (short)f2bf(Os[row * 73 + cg + 8 + j] * inv);
            }
            u16* yp = &qkv[(rowbase + q0 + row) * 3072 + cbase + cg];
            *(short8*)yp = o0;
            *(short8*)(yp + 8) = o1;
        }
        __syncthreads();  // Os/ls reads done before next pass re-zeroes
    }
}

// ---------------------------------------------------------------------------
extern "C" void kernel_launch(void* const* d_in, const int* in_sizes, int n_in,
                              void* d_out, int out_size, void* d_ws, size_t ws_size,
                              hipStream_t stream) {
    const float* x      = (const float*)d_in[0];
    const float* w_attn = (const float*)d_in[1];
    const float* b_attn = (const float*)d_in[2];
    const float* w_proj = (const float*)d_in[3];
    const float* b_proj = (const float*)d_in[4];
    float* out = (float*)d_out;

    u16* qkv = (u16*)d_ws;                      // [8192,3072] bf16 (50.33 MB)
    u16* xb  = (u16*)d_out;                     // [8192,1024] bf16 scratch (dies at GEMM1)
    u16* wTa = (u16*)((char*)d_out + 16777216); // [3072,1024] bf16 scratch (dies at GEMM1)
    u16* vT  = (u16*)d_out;                     // [64,64,2048] bf16 scratch (dies at GEMM2)

    convert_bf16<<<4096, 256, 0, stream>>>(x, xb);
    transpose_f32_bf16<<<dim3(3072 / 32, 1024 / 32), dim3(32, 8), 0, stream>>>(
        w_attn, wTa, 1024, 3072);
    gemm_bf16_bt<<<dim3(3072 / 128, 8192 / 128), 256, 0, stream>>>(
        xb, 1024, wTa, b_attn, qkv, 8192, 3072, 1024);
    transpose_v<<<dim3(64, 2, 64), dim3(32, 8), 0, stream>>>(qkv, vT);
    attn_kernel<<<dim3(64, 16), 256, 0, stream>>>(qkv, vT);
    gemm_bf16_bn<<<dim3(1024 / 128, 8192 / 128), 256, 0, stream>>>(
        qkv, 3072, w_proj, b_proj, out, 8192, 1024, 1024);
}

// Round 9
// 299.076 us; speedup vs baseline: 1.5653x; 1.5625x over previous
//
#include <hip/hip_runtime.h>

typedef __attribute__((ext_vector_type(8))) short short8;
typedef __attribute__((ext_vector_type(4))) float f32x4;
typedef unsigned short u16;
typedef unsigned int u32;

__device__ __forceinline__ float bf2f(u16 u) {
    union { u32 i; float f; } x;
    x.i = ((u32)u) << 16;
    return x.f;
}

__device__ __forceinline__ u16 f2bf(float f) {
    union { float f; u32 i; } x;
    x.f = f;
    u32 r = x.i + 0x7fffu + ((x.i >> 16) & 1u);  // RNE
    return (u16)(r >> 16);
}

// ---------------------------------------------------------------------------
// fp32 -> bf16 elementwise (n divisible by 2048)
// ---------------------------------------------------------------------------
__global__ __launch_bounds__(256) void convert_bf16(const float* __restrict__ in,
                                                    u16* __restrict__ out) {
    const long i = ((long)blockIdx.x * 256 + threadIdx.x) * 8;
    f32x4 v0 = *(const f32x4*)(in + i);
    f32x4 v1 = *(const f32x4*)(in + i + 4);
    short8 o;
#pragma unroll
    for (int j = 0; j < 4; ++j) o[j] = (short)f2bf(v0[j]);
#pragma unroll
    for (int j = 0; j < 4; ++j) o[4 + j] = (short)f2bf(v1[j]);
    *(short8*)(out + i) = o;
}

// ---------------------------------------------------------------------------
// fp32 [K][N] -> bf16 [N][K] transpose+convert
// ---------------------------------------------------------------------------
__global__ __launch_bounds__(256) void transpose_f32_bf16(const float* __restrict__ in,
                                                          u16* __restrict__ out,
                                                          int K, int N) {
    __shared__ float tile[32][33];
    const int nb = blockIdx.x * 32, kb = blockIdx.y * 32;
    const int tx = threadIdx.x, ty = threadIdx.y;  // 32 x 8
#pragma unroll
    for (int i = 0; i < 32; i += 8)
        tile[ty + i][tx] = in[(long)(kb + ty + i) * N + nb + tx];
    __syncthreads();
#pragma unroll
    for (int i = 0; i < 32; i += 8)
        out[(long)(nb + ty + i) * K + kb + tx] = f2bf(tile[tx][ty + i]);
}

// ---------------------------------------------------------------------------
// V transpose: qkv V slots [b*2048+t][2048 + h*64 + d] -> vT[bh][d][t]
// ---------------------------------------------------------------------------
__global__ __launch_bounds__(256) void transpose_v(const u16* __restrict__ qkv,
                                                   u16* __restrict__ vT) {
    __shared__ u16 tile[32][33];
    const int tb = blockIdx.x * 32;  // t
    const int db = blockIdx.y * 32;  // d
    const int bh = blockIdx.z;
    const int b = bh >> 4, h = bh & 15;
    const int tx = threadIdx.x, ty = threadIdx.y;  // 32 x 8
#pragma unroll
    for (int i = 0; i < 32; i += 8)
        tile[ty + i][tx] = qkv[((long)b * 2048 + tb + ty + i) * 3072 + 2048 + h * 64 + db + tx];
    __syncthreads();
#pragma unroll
    for (int i = 0; i < 32; i += 8)
        vT[((long)bh * 64 + db + ty + i) * 2048 + tb + tx] = tile[tx][ty + i];
}

// ---------------------------------------------------------------------------
// GEMM1: C[M,N](bf16) = A[M,K](bf16, lda) @ BT[N,K](bf16)^T + bias(f32)
// ---------------------------------------------------------------------------
__global__ __launch_bounds__(256, 2) void gemm_bf16_bt(
    const u16* __restrict__ A, int lda, const u16* __restrict__ BT,
    const float* __restrict__ bias, u16* __restrict__ C,
    int M, int N, int K) {
    __shared__ u16 As[128 * 32];
    __shared__ u16 Bs[128 * 32];
    const int tid = threadIdx.x;
    const int wv = tid >> 6, lane = tid & 63, quad = lane >> 4, L = lane & 15;
    const int wm = (wv >> 1) * 64, wn = (wv & 1) * 64;
    const long m0 = (long)blockIdx.y * 128;
    const long n0 = (long)blockIdx.x * 128;

    const u16* Ag = A + (m0 + wv * 32 + (lane >> 2)) * (long)lda + (lane & 3) * 8;
    const u16* Bg = BT + (n0 + wv * 32 + (lane >> 2)) * (long)K + (lane & 3) * 8;
    u16* AsW = &As[wv * 32 * 32];
    u16* BsW = &Bs[wv * 32 * 32];

    f32x4 zero4 = {0.f, 0.f, 0.f, 0.f};
    f32x4 acc[4][4];
#pragma unroll
    for (int i = 0; i < 4; ++i)
#pragma unroll
        for (int j = 0; j < 4; ++j) acc[i][j] = zero4;

    for (int kb = 0; kb < K; kb += 32) {
        short8 a0 = *(const short8*)(Ag + kb);
        short8 a1 = *(const short8*)(Ag + kb + (long)16 * lda);
        short8 b0 = *(const short8*)(Bg + kb);
        short8 b1 = *(const short8*)(Bg + kb + (long)16 * K);
        __syncthreads();
        *(short8*)(AsW + lane * 8) = a0;
        *(short8*)(AsW + 512 + lane * 8) = a1;
        *(short8*)(BsW + lane * 8) = b0;
        *(short8*)(BsW + 512 + lane * 8) = b1;
        __syncthreads();

        short8 af[4], bf[4];
#pragma unroll
        for (int mt = 0; mt < 4; ++mt)
            af[mt] = *(const short8*)&As[(wm + mt * 16 + L) * 32 + quad * 8];
#pragma unroll
        for (int nt = 0; nt < 4; ++nt)
            bf[nt] = *(const short8*)&Bs[(wn + nt * 16 + L) * 32 + quad * 8];
#pragma unroll
        for (int mt = 0; mt < 4; ++mt)
#pragma unroll
            for (int nt = 0; nt < 4; ++nt)
                acc[mt][nt] = __builtin_amdgcn_mfma_f32_16x16x32_bf16(
                    af[mt], bf[nt], acc[mt][nt], 0, 0, 0);
    }

#pragma unroll
    for (int nt = 0; nt < 4; ++nt) {
        const long col = n0 + wn + nt * 16 + L;
        const float bv = bias[col];
#pragma unroll
        for (int mt = 0; mt < 4; ++mt)
#pragma unroll
            for (int r = 0; r < 4; ++r) {
                const long row = m0 + wm + mt * 16 + quad * 4 + r;
                C[row * N + col] = f2bf(acc[mt][nt][r] + bv);
            }
    }
}

// ---------------------------------------------------------------------------
// GEMM2: C[M,N](f32) = A[M,K](bf16, lda) @ B[K,N](f32) + bias(f32)
// ---------------------------------------------------------------------------
__global__ __launch_bounds__(256, 2) void gemm_bf16_bn(
    const u16* __restrict__ A, int lda, const float* __restrict__ B,
    const float* __restrict__ bias, float* __restrict__ C,
    int M, int N, int K) {
    __shared__ u16 As[128 * 32];
    __shared__ u16 Bs[128 * 32];
    const int tid = threadIdx.x;
    const int wv = tid >> 6, lane = tid & 63, quad = lane >> 4, L = lane & 15;
    const int wm = (wv >> 1) * 64, wn = (wv & 1) * 64;
    const long m0 = (long)blockIdx.y * 128;
    const long n0 = (long)blockIdx.x * 128;

    const u16* Ag = A + (m0 + wv * 32 + (lane >> 2)) * (long)lda + (lane & 3) * 8;
    u16* AsW = &As[wv * 32 * 32];

    f32x4 zero4 = {0.f, 0.f, 0.f, 0.f};
    f32x4 acc[4][4];
#pragma unroll
    for (int i = 0; i < 4; ++i)
#pragma unroll
        for (int j = 0; j < 4; ++j) acc[i][j] = zero4;

    for (int kb = 0; kb < K; kb += 32) {
        short8 a0 = *(const short8*)(Ag + kb);
        short8 a1 = *(const short8*)(Ag + kb + (long)16 * lda);
        short8 p[2];
#pragma unroll
        for (int i = 0; i < 2; ++i) {
            const int c = tid + i * 256;
            const int n = c >> 2, k8 = (c & 3) * 8;
            const float* bp = B + (long)(kb + k8) * N + n0 + n;
#pragma unroll
            for (int j = 0; j < 8; ++j) p[i][j] = (short)f2bf(bp[(long)j * N]);
        }
        __syncthreads();
        *(short8*)(AsW + lane * 8) = a0;
        *(short8*)(AsW + 512 + lane * 8) = a1;
        *(short8*)(&Bs[tid * 8]) = p[0];
        *(short8*)(&Bs[(tid + 256) * 8]) = p[1];
        __syncthreads();

        short8 af[4], bf[4];
#pragma unroll
        for (int mt = 0; mt < 4; ++mt)
            af[mt] = *(const short8*)&As[(wm + mt * 16 + L) * 32 + quad * 8];
#pragma unroll
        for (int nt = 0; nt < 4; ++nt)
            bf[nt] = *(const short8*)&Bs[(wn + nt * 16 + L) * 32 + quad * 8];
#pragma unroll
        for (int mt = 0; mt < 4; ++mt)
#pragma unroll
            for (int nt = 0; nt < 4; ++nt)
                acc[mt][nt] = __builtin_amdgcn_mfma_f32_16x16x32_bf16(
                    af[mt], bf[nt], acc[mt][nt], 0, 0, 0);
    }

#pragma unroll
    for (int nt = 0; nt < 4; ++nt) {
        const long col = n0 + wn + nt * 16 + L;
        const float bv = bias[col];
#pragma unroll
        for (int mt = 0; mt < 4; ++mt)
#pragma unroll
            for (int r = 0; r < 4; ++r) {
                const long row = m0 + wm + mt * 16 + quad * 4 + r;
                C[row * N + col] = acc[mt][nt][r] + bv;
            }
    }
}

// ---------------------------------------------------------------------------
// Flash attention (causal), bf16, fixed-max softmax (m=20). 32-key tiles of
// K and pre-transposed V staged COALESCED into double-buffered LDS (pitches
// 72/40: conflict-free b128 at the 8-group floor), register prefetch one tile
// ahead, ONE barrier per tile. 4 waves split the 64 queries (q-split; each
// wave owns its output rows -> no combine). Workgroup does the qtile pair
// (31-by, by): constant 66 tile-units -> perfectly balanced grid 64x16 =
// exactly 4 blocks/CU, all resident (LDS 28 KB -> cap 5).
// Output written into the Q slots of qkv (race-free, same proof as R7).
// ---------------------------------------------------------------------------
#define AT_T 2048

__global__ __launch_bounds__(256) void attn_kernel(u16* __restrict__ qkv,
                                                   const u16* __restrict__ vT) {
    __shared__ u16 Kt[2][32 * 72];   // [key][d]  tile, pitch 72
    __shared__ u16 Vt[2][64 * 40];   // [d][key]  tile, pitch 40
    __shared__ u16 Ps[4][16 * 72];   // per-wave P round-trip
    const int tid = threadIdx.x;
    const int wv = tid >> 6, lane = tid & 63, quad = lane >> 4, L = lane & 15;
    const int bh = blockIdx.x;
    const int b = bh >> 4, h = bh & 15;
    const long rowbase = (long)b * AT_T;
    const long cbase = (long)h * 64;

    // staging geometry (coalesced: consecutive tid -> consecutive 16B)
    const int krow = tid >> 3, kc = tid & 7;  // K: 32 rows x 8 chunks
    const int vrow = tid >> 2, vc = tid & 3;  // V: 64 rows x 4 chunks
    const u16* Kg = qkv + (rowbase + krow) * 3072 + 1024 + cbase + kc * 8;
    const u16* Vg = vT + ((long)bh * 64 + vrow) * 2048 + vc * 8;

    // ones B-fragment: column 0 accumulates row sums
    short8 ones;
#pragma unroll
    for (int j = 0; j < 8; ++j) ones[j] = (L == 0) ? (short)0x3F80 : (short)0;

    f32x4 zero4 = {0.f, 0.f, 0.f, 0.f};
    u16* PsW = Ps[wv];

    for (int pass = 0; pass < 2; ++pass) {
        const int qtile = (pass == 0) ? (31 - (int)blockIdx.y) : (int)blockIdx.y;
        const int q0 = qtile * 64;
        const int qw0 = q0 + wv * 16;  // this wave's 16 queries
        const int nkb = 2 * qtile + 2;

        // Q fragments (A layout m=L, k=quad*8+j)
        short8 qf[2];
#pragma unroll
        for (int s = 0; s < 2; ++s)
            qf[s] = *(const short8*)&qkv[(rowbase + qw0 + L) * 3072 + cbase + s * 32 + quad * 8];

        f32x4 accO[4], accL = zero4;
#pragma unroll
        for (int nt = 0; nt < 4; ++nt) accO[nt] = zero4;

        // preload tile 0 into buf 0
        {
            short8 k0r = *(const short8*)Kg;
            short8 v0r = *(const short8*)Vg;
            *(short8*)&Kt[0][krow * 72 + kc * 8] = k0r;
            *(short8*)&Vt[0][vrow * 40 + vc * 8] = v0r;
        }
        __syncthreads();

        int p = 0;
        for (int kb = 0; kb < nkb; ++kb) {
            const int k0 = kb * 32;
            const bool more = (kb + 1) < nkb;
            // register prefetch of next tile (issued, consumed after compute)
            short8 knx, vnx;
            if (more) {
                knx = *(const short8*)(Kg + (long)(k0 + 32) * 3072);
                vnx = *(const short8*)(Vg + k0 + 32);
            }

            if (k0 <= qw0 + 15) {  // tile not fully masked for this wave
                // QK^T: 16 queries x 32 keys
                f32x4 sA[2];
#pragma unroll
                for (int nt = 0; nt < 2; ++nt) {
                    short8 kf0 = *(const short8*)&Kt[p][(nt * 16 + L) * 72 + quad * 8];
                    short8 kf1 = *(const short8*)&Kt[p][(nt * 16 + L) * 72 + 32 + quad * 8];
                    f32x4 z = __builtin_amdgcn_mfma_f32_16x16x32_bf16(qf[0], kf0, zero4, 0, 0, 0);
                    sA[nt] = __builtin_amdgcn_mfma_f32_16x16x32_bf16(qf[1], kf1, z, 0, 0, 0);
                }
                // p = exp(s*0.125 - 20), trunc-pack bf16 (bias cancels in O/l)
                if (k0 + 31 > qw0) {  // partial diagonal: mask
#pragma unroll
                    for (int nt = 0; nt < 2; ++nt) {
                        const int key = k0 + nt * 16 + L;
#pragma unroll
                        for (int r = 0; r < 4; ++r) {
                            const int qq = qw0 + quad * 4 + r;
                            const float v = (key <= qq) ? fmaf(sA[nt][r], 0.125f, -20.0f) : -1e30f;
                            PsW[(quad * 4 + r) * 72 + nt * 16 + L] =
                                (u16)(__float_as_uint(__expf(v)) >> 16);
                        }
                    }
                } else {
#pragma unroll
                    for (int nt = 0; nt < 2; ++nt)
#pragma unroll
                        for (int r = 0; r < 4; ++r) {
                            const float pv = __expf(fmaf(sA[nt][r], 0.125f, -20.0f));
                            PsW[(quad * 4 + r) * 72 + nt * 16 + L] =
                                (u16)(__float_as_uint(pv) >> 16);
                        }
                }
                // PV + row-sum: P A-frag covers all 32 keys in one read
                short8 pf = *(const short8*)&PsW[L * 72 + quad * 8];
                accL = __builtin_amdgcn_mfma_f32_16x16x32_bf16(pf, ones, accL, 0, 0, 0);
#pragma unroll
                for (int nt = 0; nt < 4; ++nt) {
                    short8 vf = *(const short8*)&Vt[p][(nt * 16 + L) * 40 + quad * 8];
                    accO[nt] = __builtin_amdgcn_mfma_f32_16x16x32_bf16(pf, vf, accO[nt], 0, 0, 0);
                }
            }

            // write prefetched tile into the other buffer (read 2 iters ago)
            if (more) {
                *(short8*)&Kt[p ^ 1][krow * 72 + kc * 8] = knx;
                *(short8*)&Vt[p ^ 1][vrow * 40 + vc * 8] = vnx;
            }
            __syncthreads();
            p ^= 1;
        }

        // normalize + write into Q slots (l in column 0: lane quad*16, reg r)
#pragma unroll
        for (int r = 0; r < 4; ++r) {
            const float l = __shfl(accL[r], lane & 48);
            const float inv = 1.f / l;
            const long orow = (rowbase + qw0 + quad * 4 + r) * 3072 + cbase;
#pragma unroll
            for (int nt = 0; nt < 4; ++nt)
                qkv[orow + nt * 16 + L] = f2bf(accO[nt][r] * inv);
        }
    }
}

// ---------------------------------------------------------------------------
extern "C" void kernel_launch(void* const* d_in, const int* in_sizes, int n_in,
                              void* d_out, int out_size, void* d_ws, size_t ws_size,
                              hipStream_t stream) {
    const float* x      = (const float*)d_in[0];
    const float* w_attn = (const float*)d_in[1];
    const float* b_attn = (const float*)d_in[2];
    const float* w_proj = (const float*)d_in[3];
    const float* b_proj = (const float*)d_in[4];
    float* out = (float*)d_out;

    u16* qkv = (u16*)d_ws;                      // [8192,3072] bf16 (50.33 MB)
    u16* xb  = (u16*)d_out;                     // [8192,1024] bf16 scratch (dies at GEMM1)
    u16* wTa = (u16*)((char*)d_out + 16777216); // [3072,1024] bf16 scratch (dies at GEMM1)
    u16* vT  = (u16*)d_out;                     // [64,64,2048] bf16 scratch (dies at GEMM2)

    convert_bf16<<<4096, 256, 0, stream>>>(x, xb);
    transpose_f32_bf16<<<dim3(3072 / 32, 1024 / 32), dim3(32, 8), 0, stream>>>(
        w_attn, wTa, 1024, 3072);
    gemm_bf16_bt<<<dim3(3072 / 128, 8192 / 128), 256, 0, stream>>>(
        xb, 1024, wTa, b_attn, qkv, 8192, 3072, 1024);
    transpose_v<<<dim3(64, 2, 64), dim3(32, 8), 0, stream>>>(qkv, vT);
    attn_kernel<<<dim3(64, 16), 256, 0, stream>>>(qkv, vT);
    gemm_bf16_bn<<<dim3(1024 / 128, 8192 / 128), 256, 0, stream>>>(
        qkv, 3072, w_proj, b_proj, out, 8192, 1024, 1024);
}